// Round 11
// baseline (191.441 us; speedup 1.0000x reference)
//
#include <hip/hip_runtime.h>
#include <hip/hip_bf16.h>

typedef __bf16 bf16x8 __attribute__((ext_vector_type(8)));
typedef short s16x4 __attribute__((ext_vector_type(4)));
typedef float f32x4 __attribute__((ext_vector_type(4)));
typedef unsigned short u16x8 __attribute__((ext_vector_type(8)));

#define MFMA_K32(a, b, c) __builtin_amdgcn_mfma_f32_16x16x32_bf16(a, b, c, 0, 0, 0)

// 16x16x16 bf16 MFMA; builtin exists only in device pass.
static __device__ __forceinline__ f32x4 mfma_k16(s16x4 a, s16x4 b, f32x4 c) {
#ifdef __HIP_DEVICE_COMPILE__
    return __builtin_amdgcn_mfma_f32_16x16x16bf16_1k(a, b, c, 0, 0, 0);
#else
    return c;
#endif
}

static __device__ __forceinline__ float fast_exp2(float x) {
#ifdef __HIP_DEVICE_COMPILE__
    return __builtin_amdgcn_exp2f(x);
#else
    return x;
#endif
}

static __device__ __forceinline__ void prio_hi() {
#ifdef __HIP_DEVICE_COMPILE__
    __builtin_amdgcn_s_setprio(1);
#endif
}
static __device__ __forceinline__ void prio_lo() {
#ifdef __HIP_DEVICE_COMPILE__
    __builtin_amdgcn_s_setprio(0);
#endif
}

// async global->LDS, 16B per lane; lds dest = wave-uniform base + lane*16
#define GLL16(gp, lp)                                              \
    __builtin_amdgcn_global_load_lds(                              \
        (const __attribute__((address_space(1))) void*)(gp),       \
        (__attribute__((address_space(3))) void*)(lp), 16, 0, 0)

// round-to-nearest-even fp32 -> bf16 (finite inputs only)
static __device__ __forceinline__ unsigned short f2bf(float f) {
    unsigned int u = __float_as_uint(f);
    u += 0x7fffu + ((u >> 16) & 1u);
    return (unsigned short)(u >> 16);
}

// packed fp32x2 -> bf16x2 (RNE) via gfx950 v_cvt_pk_bf16_f32 when available
static __device__ __forceinline__ unsigned int cvtpk_bf16(float lo, float hi) {
#if defined(__HIP_DEVICE_COMPILE__) && __has_builtin(__builtin_amdgcn_cvt_pk_bf16_f32)
    typedef __bf16 bf16x2 __attribute__((ext_vector_type(2)));
    bf16x2 r = __builtin_amdgcn_cvt_pk_bf16_f32(lo, hi);
    return __builtin_bit_cast(unsigned int, r);
#else
    return (unsigned int)f2bf(lo) | ((unsigned int)f2bf(hi) << 16);
#endif
}

#define LOG2E 1.44269504088896340736f

// ---------------------------------------------------------------------------
// Fused prep (R10 version): transpose+cast w_qkv/w_out (64x64 tiles, float4
// loads, padded LDS, uint4 bf16 stores), rmsnorm x->xn. R10 measured: prep
// is NOT a major cost (vectorization didn't move the total) - kept because
// verified and not worse.
// ---------------------------------------------------------------------------
__global__ __launch_bounds__(256) void prep_k(
    const float* __restrict__ x, const float* __restrict__ gamma,
    const float* __restrict__ w_qkv, const float* __restrict__ w_out,
    unsigned short* __restrict__ xn, unsigned short* __restrict__ wtq,
    unsigned short* __restrict__ wto) {
    __shared__ float sm[64][65];  // 16640 B
    int bid = blockIdx.x, tid = threadIdx.x;
    if (bid < 1024) {  // transpose paths (block-uniform branch)
        const float* in;
        unsigned short* out;
        int R = 1024, C, bx, by;
        if (bid < 768) { in = w_qkv; out = wtq; C = 3072; bx = bid % 48; by = bid / 48; }
        else { int b2 = bid - 768; in = w_out; out = wto; C = 1024; bx = b2 % 16; by = b2 / 16; }
        int c0 = bx * 64, r0 = by * 64;
        int lr = tid >> 4, lc4 = (tid & 15) * 4;
#pragma unroll
        for (int i = 0; i < 4; i++) {
            int row = lr + i * 16;
            float4 v = *(const float4*)(in + (size_t)(r0 + row) * C + c0 + lc4);
            sm[row][lc4] = v.x;
            sm[row][lc4 + 1] = v.y;
            sm[row][lc4 + 2] = v.z;
            sm[row][lc4 + 3] = v.w;
        }
        __syncthreads();
#pragma unroll
        for (int kk = 0; kk < 2; kk++) {
            int j = (tid >> 3) + kk * 32;  // out row (= in col) 0..63
            int r8 = (tid & 7) * 8;        // out col (= in row) base
            uint4 pk;
            pk.x = cvtpk_bf16(sm[r8 + 0][j], sm[r8 + 1][j]);
            pk.y = cvtpk_bf16(sm[r8 + 2][j], sm[r8 + 3][j]);
            pk.z = cvtpk_bf16(sm[r8 + 4][j], sm[r8 + 5][j]);
            pk.w = cvtpk_bf16(sm[r8 + 6][j], sm[r8 + 7][j]);
            *(uint4*)(out + (size_t)(c0 + j) * R + r0 + r8) = pk;
        }
    } else {  // rmsnorm
        int row = bid - 1024;
        const float* xr = x + (size_t)row * 1024;
        float4 v = *(const float4*)(xr + tid * 4);
        float ss = v.x * v.x + v.y * v.y + v.z * v.z + v.w * v.w;
#pragma unroll
        for (int off = 1; off < 64; off <<= 1) ss += __shfl_xor(ss, off, 64);
        if ((tid & 63) == 0) sm[0][tid >> 6] = ss;
        __syncthreads();
        float tot = sm[0][0] + sm[0][1] + sm[0][2] + sm[0][3];
        float f = 32.0f / fmaxf(sqrtf(tot), 1e-12f);  // sqrt(1024)=32
        float4 g = *(const float4*)(gamma + tid * 4);
        uint2 o;
        o.x = cvtpk_bf16(v.x * f * g.x, v.y * f * g.y);
        o.y = cvtpk_bf16(v.z * f * g.z, v.w * f * g.w);
        *(uint2*)(xn + (size_t)row * 1024 + tid * 4) = o;
    }
}

// ---------------------------------------------------------------------------
// GEMM (m97 structure, R6 config): C[M,N] = A[M,K] * BT[N,K]^T.
// BM x 128 tile, BK=32, global_load_lds width-16, unpadded LDS.
// MODE 0: fp32 store; with KS=2, blockIdx.z=0 -> C, z=1 -> C1 (separate
// partial buffer; NO atomics - R7's atomic epilogue regression avoided; a
// trivial add kernel combines). MODE 1: qkv epilogue.
// R10 accounting model: per-K-step wall cost ~1.2-1.5us is stage+drain+
// barrier-dominated, nearly independent of tile FLOPs -> gemm2 at 32 steps
// x 2 blocks/CU ~ 45us despite 4x fewer FLOPs than gemm1. KS=2 halves the
// serial steps and doubles co-residency (1024 blocks = 4/CU, m97's proven
// overlap config). R9: T2 swizzle+BK=64 null at 2-phase (regime gate).
// ---------------------------------------------------------------------------
template <int MODE, int BM, int KS>
__global__ __launch_bounds__(256) void gemm_bt_k(
    const unsigned short* __restrict__ A, const unsigned short* __restrict__ BT,
    float* __restrict__ C, float* __restrict__ C1, unsigned short* __restrict__ qw,
    unsigned short* __restrict__ kw, unsigned short* __restrict__ vw,
    int M, int N, int K) {
    constexpr int RT = 4;
    constexpr int CT = (BM == 128) ? 4 : 2;
    __shared__ unsigned short As[BM][32];
    __shared__ unsigned short Bs[128][32];
    int tid = threadIdx.x;
    int wave = tid >> 6, lane = tid & 63, quad = lane >> 4, l16 = lane & 15;
    int wrb, wcb;
    if constexpr (BM == 128) { wrb = (wave >> 1) * 64; wcb = (wave & 1) * 64; }
    else { wrb = 0; wcb = wave * 32; }
    int m0 = blockIdx.y * BM, n0 = blockIdx.x * 128;
    int k_beg = 0, k_end = K;
    float* Cdst = C;
    if constexpr (KS > 1) {
        int kz = blockIdx.z;
        k_beg = kz * (K / KS);
        k_end = k_beg + K / KS;
        if (kz) Cdst = C1;
    }
    int lrow = lane >> 2, lcol = (lane & 3) * 8;  // lane -> (row,col) in 16x32 chunk
    const unsigned short *Ag0, *Ag1 = nullptr;
    if constexpr (BM == 128) {
        Ag0 = A + (size_t)(m0 + wave * 32 + lrow) * K + lcol;
        Ag1 = A + (size_t)(m0 + wave * 32 + 16 + lrow) * K + lcol;
    } else {
        Ag0 = A + (size_t)(m0 + wave * 16 + lrow) * K + lcol;
    }
    const unsigned short* Bg0 = BT + (size_t)(n0 + wave * 32 + lrow) * K + lcol;
    const unsigned short* Bg1 = BT + (size_t)(n0 + wave * 32 + 16 + lrow) * K + lcol;
    f32x4 acc[RT][CT] = {};
    for (int k0 = k_beg; k0 < k_end; k0 += 32) {
        __syncthreads();  // prior ds_reads done before overwrite
        if constexpr (BM == 128) {
            GLL16(Ag0 + k0, &As[wave * 32][0]);
            GLL16(Ag1 + k0, &As[wave * 32 + 16][0]);
        } else {
            GLL16(Ag0 + k0, &As[wave * 16][0]);
        }
        GLL16(Bg0 + k0, &Bs[wave * 32][0]);
        GLL16(Bg1 + k0, &Bs[wave * 32 + 16][0]);
        __syncthreads();  // drains vmcnt: staging complete
        bf16x8 af[RT], bfr[CT];
#pragma unroll
        for (int t = 0; t < RT; t++)
            af[t] = *(const bf16x8*)&As[wrb + t * 16 + l16][quad * 8];
#pragma unroll
        for (int t = 0; t < CT; t++)
            bfr[t] = *(const bf16x8*)&Bs[wcb + t * 16 + l16][quad * 8];
#pragma unroll
        for (int rt = 0; rt < RT; rt++)
#pragma unroll
            for (int ct = 0; ct < CT; ct++)
                acc[rt][ct] = MFMA_K32(af[rt], bfr[ct], acc[rt][ct]);
    }
#pragma unroll
    for (int rt = 0; rt < RT; rt++) {
        int mb = m0 + wrb + rt * 16 + quad * 4;
        int b = mb >> 11, nn = mb & 2047;
#pragma unroll
        for (int ct = 0; ct < CT; ct++) {
            int col = n0 + wcb + ct * 16 + l16;
            if (MODE == 0) {
#pragma unroll
                for (int r = 0; r < 4; r++)
                    Cdst[(size_t)(mb + r) * N + col] = acc[rt][ct][r];
            } else {
                int sec = col >> 10, ci = col & 1023;
                int hh = ci >> 6, dd = ci & 63;
                int bh = b * 16 + hh;
                if (sec == 0) {
#pragma unroll
                    for (int r = 0; r < 4; r++)
                        qw[((size_t)bh * 2048 + nn + r) * 64 + dd] =
                            f2bf(acc[rt][ct][r] * (0.125f * LOG2E));
                } else if (sec == 1) {
#pragma unroll
                    for (int r = 0; r < 4; r++)
                        kw[((size_t)bh * 2048 + nn + r) * 64 + dd] = f2bf(acc[rt][ct][r]);
                } else {
                    uint2 pk;
                    pk.x = cvtpk_bf16(acc[rt][ct][0], acc[rt][ct][1]);
                    pk.y = cvtpk_bf16(acc[rt][ct][2], acc[rt][ct][3]);
                    *(uint2*)&vw[((size_t)bh * 64 + dd) * 2048 + nn] = pk;
                }
            }
        }
    }
}

// out += p, float4 per lane. 4096 blocks x 256 threads x 4 floats = 4.19M.
__global__ __launch_bounds__(256) void add_k(float* __restrict__ out,
                                             const float* __restrict__ p) {
    size_t i = ((size_t)blockIdx.x * 256 + threadIdx.x) * 4;
    float4 a = *(const float4*)(out + i);
    float4 b = *(const float4*)(p + i);
    a.x += b.x;
    a.y += b.y;
    a.z += b.z;
    a.w += b.w;
    *(float4*)(out + i) = a;
}

// ---------------------------------------------------------------------------
// Causal flash attention, key-split 8-wave blocks (R6 structure, EXACT —
// proven 46.4-46.7us across R6/R7/R9/R10). Chain-cut softmax (per-lane max;
// scalar __any ballot gates rare reduce+rescale; P bounded by 2^8, T13),
// per-lane lrun reduced once in epilogue, KVBLK=32, 1 barrier/tile, dbuf +
// reg prefetch. Groups of 4 waves split the key range; merge via LDS
// (fully-masked rows killed by a1->0). (512,4): VGPR 40 -> 4 blocks/CU.
// R8: KVBLK=64 cut residency 4->2 blocks/CU, regressed; do not revisit.
// ---------------------------------------------------------------------------
__global__ __launch_bounds__(512, 4) void attn_k(
    const unsigned short* __restrict__ q, const unsigned short* __restrict__ k,
    const unsigned short* __restrict__ vt, unsigned short* __restrict__ o) {
    // LDS union: [group][buf] K tiles (32x64, pad 72) + V tiles (64x32, pad 40);
    // epilogue overlays Osm[64][68] f32 on the K region, msm/lsm on V region.
    __shared__ __align__(16) char smem[38912];
    typedef unsigned short ush;
    ush(*Ks)[2][32][72] = (ush(*)[2][32][72])smem;            // 18432 B
    ush(*Vt)[2][64][40] = (ush(*)[2][64][40])(smem + 18432);  // 20480 B
    float(*Osm)[68] = (float(*)[68])smem;                     // 17408 B (<= K region)
    float* msm = (float*)(smem + 18432);                      // 256 B (in V region)
    float* lsm = msm + 64;

    int bh = blockIdx.x;
    int qt = 31 - (int)blockIdx.y;  // heavy-first LPT order
    int tid = threadIdx.x, wave = tid >> 6, lane = tid & 63;
    int quad = lane >> 4, l16 = lane & 15;
    int g = wave >> 2, wq = wave & 3;
    int b = bh >> 4, h = bh & 15;
    const ush* qg = q + (size_t)bh * 2048 * 64;
    const ush* kg = k + (size_t)bh * 2048 * 64;
    const ush* vg = vt + (size_t)bh * 64 * 2048;

    // staging map: 256 threads/group; K: 32 rows x 64 cols; V: 64 d x 32 keys
    int ti = wq * 64 + lane;
    int kr = ti >> 3, kc = (ti & 7) * 8;
    int vr = ti >> 2, vc = (ti & 3) * 8;
    const ush* Kg = kg + (size_t)kr * 64 + kc;
    const ush* Vg = vg + (size_t)vr * 2048 + vc;

    int row_l = wq * 16 + l16;    // local q row 0..63
    int q0w = qt * 64 + wq * 16;  // global q row base for this wave
    bf16x8 bq[2];                 // Q^T B-operand: [k=d=ks*32+quad*8+j][n=qrow=l16]
#pragma unroll
    for (int ks = 0; ks < 2; ks++)
        bq[ks] = *(const bf16x8*)&qg[(size_t)(q0w + l16) * 64 + ks * 32 + quad * 8];

    f32x4 ot[4] = {};                 // Ot C-layout: [d=dt*16+quad*4+r][qrow=l16]
    float mrun = -1e30f, lrun = 0.f;  // lrun is a PER-LANE partial (reduced at end)
    int nT = qt + 1;                  // tiles per group (equal for both groups)
    int kt0 = g ? (qt + 1) : 0;

    u16x8 pk, pv;  // prefetch registers
    // preload first tile into buf 0
    pk = *(const u16x8*)(Kg + (size_t)kt0 * 2048);
    pv = *(const u16x8*)(Vg + kt0 * 32);
    *(u16x8*)&Ks[g][0][kr][kc] = pk;
    *(u16x8*)&Vt[g][0][vr][vc] = pv;
    __syncthreads();

    for (int i = 0; i < nT; i++) {
        int cb = i & 1, kt = kt0 + i;
        bool pf = (i + 1 < nT);
        if (pf) {  // issue next tile's global loads early (wave-uniform branch)
            pk = *(const u16x8*)(Kg + (size_t)(kt + 1) * 2048);
            pv = *(const u16x8*)(Vg + (kt + 1) * 32);
        }
        // St[key=ct*16+quad*4+r][qrow=l16] = K . Q^T
        f32x4 sf[2];
        prio_hi();
#pragma unroll
        for (int ct = 0; ct < 2; ct++) {
            bf16x8 ak0 = *(const bf16x8*)&Ks[g][cb][ct * 16 + l16][quad * 8];
            bf16x8 ak1 = *(const bf16x8*)&Ks[g][cb][ct * 16 + l16][32 + quad * 8];
            f32x4 s = {};
            s = MFMA_K32(ak0, bq[0], s);
            s = MFMA_K32(ak1, bq[1], s);
            sf[ct] = s;
        }
        prio_lo();
        if (kt >= 2 * qt) {  // tiles that can touch the diagonal
#pragma unroll
            for (int ct = 0; ct < 2; ct++)
#pragma unroll
                for (int r = 0; r < 4; r++)
                    if (kt * 32 + ct * 16 + quad * 4 + r > qt * 64 + row_l)
                        sf[ct][r] = -1e30f;
        }
        // chain-cut online softmax (exp2 domain; log2e pre-folded into q):
        // per-lane max only in the common path; no DS shuffles.
        float t0 = fmaxf(sf[0][0], sf[0][1]), t1 = fmaxf(sf[0][2], sf[0][3]);
        float t2 = fmaxf(sf[1][0], sf[1][1]), t3 = fmaxf(sf[1][2], sf[1][3]);
        float mx_l = fmaxf(fmaxf(t0, t1), fmaxf(t2, t3));
        if (__any(mx_l > mrun + 8.0f)) {  // rare: full reduce + rescale
            float mx = fmaxf(mx_l, __shfl_xor(mx_l, 16, 64));
            mx = fmaxf(mx, __shfl_xor(mx, 32, 64));
            float mnew = fmaxf(mrun, mx);
            float al = fast_exp2(mrun - mnew);
            mrun = mnew;
            lrun *= al;
#pragma unroll
            for (int dt = 0; dt < 4; dt++)
#pragma unroll
                for (int r = 0; r < 4; r++) ot[dt][r] *= al;
        }
        float rs = 0.f;
#pragma unroll
        for (int ct = 0; ct < 2; ct++)
#pragma unroll
            for (int r = 0; r < 4; r++) {
                float p = fast_exp2(sf[ct][r] - mrun);  // bounded by 2^8
                sf[ct][r] = p;
                rs += p;
            }
        lrun += rs;  // per-lane partial; cross-quad reduce deferred to epilogue
        // P -> packed bf16 B-fragments for 16x16x16 (k=quad*4+j = C-layout)
        s16x4 bpr[2];
#pragma unroll
        for (int ct = 0; ct < 2; ct++) {
            uint2 u;
            u.x = cvtpk_bf16(sf[ct][0], sf[ct][1]);
            u.y = cvtpk_bf16(sf[ct][2], sf[ct][3]);
            bpr[ct] = __builtin_bit_cast(s16x4, u);
        }
        // Ot += V^T * P^T
        prio_hi();
#pragma unroll
        for (int dt = 0; dt < 4; dt++) {
#pragma unroll
            for (int ct = 0; ct < 2; ct++) {
                s16x4 av = *(const s16x4*)&Vt[g][cb][dt * 16 + l16][ct * 16 + quad * 4];
                ot[dt] = mfma_k16(av, bpr[ct], ot[dt]);
            }
        }
        prio_lo();
        if (pf) {  // write prefetched tile to the other buffer
            *(u16x8*)&Ks[g][1 - cb][kr][kc] = pk;
            *(u16x8*)&Vt[g][1 - cb][vr][vc] = pv;
        }
        __syncthreads();  // single barrier per tile
    }

    // deferred cross-quad sum reduce (once, instead of 2 shuffles per tile)
    lrun += __shfl_xor(lrun, 16, 64);
    lrun += __shfl_xor(lrun, 32, 64);

    // ---- cross-group merge (group 1 -> LDS, group 0 combines + writes) ----
    if (g == 1) {
        msm[row_l] = mrun;  // quads duplicate-write identical values: benign
        lsm[row_l] = lrun;
#pragma unroll
        for (int dt = 0; dt < 4; dt++)
            *(f32x4*)&Osm[row_l][dt * 16 + quad * 4] = ot[dt];
    }
    __syncthreads();
    if (g == 0) {
        float m1 = msm[row_l], l1 = lsm[row_l];
        float mmax = fmaxf(mrun, m1);
        float a0 = fast_exp2(mrun - mmax), a1 = fast_exp2(m1 - mmax);
        float inv = 1.0f / (a0 * lrun + a1 * l1);
        float s0 = a0 * inv, s1 = a1 * inv;
        size_t rowbase = ((size_t)b * 2048 + qt * 64 + row_l) * 1024 + h * 64;
#pragma unroll
        for (int dt = 0; dt < 4; dt++) {
            f32x4 o1 = *(const f32x4*)&Osm[row_l][dt * 16 + quad * 4];
            uint2 pkk;
            pkk.x = cvtpk_bf16(ot[dt][0] * s0 + o1[0] * s1,
                               ot[dt][1] * s0 + o1[1] * s1);
            pkk.y = cvtpk_bf16(ot[dt][2] * s0 + o1[2] * s1,
                               ot[dt][3] * s0 + o1[3] * s1);
            *(uint2*)&o[rowbase + dt * 16 + quad * 4] = pkk;
        }
    }
}

extern "C" void kernel_launch(void* const* d_in, const int* in_sizes, int n_in,
                              void* d_out, int out_size, void* d_ws, size_t ws_size,
                              hipStream_t stream) {
    const float* x = (const float*)d_in[0];       // [2,2048,1024]
    const float* gamma = (const float*)d_in[1];   // [1024]
    const float* w_qkv = (const float*)d_in[2];   // [1024,3072]
    const float* w_out = (const float*)d_in[3];   // [1024,1024]
    float* out = (float*)d_out;                   // [2,2048,1024] fp32
    char* ws = (char*)d_ws;

    unsigned short* xn = (unsigned short*)(ws);              // 8 MB (reused as ao)
    unsigned short* wtq = (unsigned short*)(ws + 8388608);   // 6 MB  [3072][1024]
    unsigned short* wto = (unsigned short*)(ws + 14680064);  // 2 MB  [1024][1024]
    unsigned short* qw = (unsigned short*)(ws + 16777216);   // 8 MB  [32][2048][64]
    unsigned short* kw = (unsigned short*)(ws + 25165824);   // 8 MB  [32][2048][64]
    unsigned short* vw = (unsigned short*)(ws + 33554432);   // 8 MB  [32][64][2048]
    unsigned short* ao = xn;                                 // reuse after QKV GEMM
    // split-K partial for gemm2: reuses qw/kw region (16 MB, dead after attn)
    float* part1 = (float*)(ws + 16777216);

    prep_k<<<5120, 256, 0, stream>>>(x, gamma, w_qkv, w_out, xn, wtq, wto);
    gemm_bt_k<1, 128, 1><<<dim3(24, 32), 256, 0, stream>>>(
        xn, wtq, nullptr, nullptr, qw, kw, vw, 4096, 3072, 1024);
    attn_k<<<dim3(32, 32), 512, 0, stream>>>(qw, kw, vw, ao);
    // split-K=2, separate outputs (z=0 -> out, z=1 -> part1), no atomics;
    // 1024 blocks = 4/CU, 16 steps each (R10 model: step cost ~ constant,
    // so halving steps + doubling overlap ≈ halves wall time).
    gemm_bt_k<0, 64, 2><<<dim3(8, 64, 2), 256, 0, stream>>>(
        ao, wto, out, part1, nullptr, nullptr, nullptr, 4096, 1024, 1024);
    add_k<<<4096, 256, 0, stream>>>(out, part1);
}

// Round 12
// 175.625 us; speedup vs baseline: 1.0901x; 1.0901x over previous
//
#include <hip/hip_runtime.h>
#include <hip/hip_bf16.h>

typedef __bf16 bf16x8 __attribute__((ext_vector_type(8)));
typedef short s16x4 __attribute__((ext_vector_type(4)));
typedef float f32x4 __attribute__((ext_vector_type(4)));
typedef unsigned short u16x8 __attribute__((ext_vector_type(8)));

#define MFMA_K32(a, b, c) __builtin_amdgcn_mfma_f32_16x16x32_bf16(a, b, c, 0, 0, 0)

// 16x16x16 bf16 MFMA; builtin exists only in device pass.
static __device__ __forceinline__ f32x4 mfma_k16(s16x4 a, s16x4 b, f32x4 c) {
#ifdef __HIP_DEVICE_COMPILE__
    return __builtin_amdgcn_mfma_f32_16x16x16bf16_1k(a, b, c, 0, 0, 0);
#else
    return c;
#endif
}

static __device__ __forceinline__ float fast_exp2(float x) {
#ifdef __HIP_DEVICE_COMPILE__
    return __builtin_amdgcn_exp2f(x);
#else
    return x;
#endif
}

static __device__ __forceinline__ void prio_hi() {
#ifdef __HIP_DEVICE_COMPILE__
    __builtin_amdgcn_s_setprio(1);
#endif
}
static __device__ __forceinline__ void prio_lo() {
#ifdef __HIP_DEVICE_COMPILE__
    __builtin_amdgcn_s_setprio(0);
#endif
}

// counted vmcnt waits (T4): keep N staging loads in flight across barriers.
static __device__ __forceinline__ void wait_vmcnt_0() {
#ifdef __HIP_DEVICE_COMPILE__
    asm volatile("s_waitcnt vmcnt(0)" ::: "memory");
    __builtin_amdgcn_sched_barrier(0);
#endif
}
static __device__ __forceinline__ void wait_vmcnt_3() {
#ifdef __HIP_DEVICE_COMPILE__
    asm volatile("s_waitcnt vmcnt(3)" ::: "memory");
    __builtin_amdgcn_sched_barrier(0);
#endif
}
static __device__ __forceinline__ void wait_vmcnt_4() {
#ifdef __HIP_DEVICE_COMPILE__
    asm volatile("s_waitcnt vmcnt(4)" ::: "memory");
    __builtin_amdgcn_sched_barrier(0);
#endif
}
static __device__ __forceinline__ void raw_barrier() {
#ifdef __HIP_DEVICE_COMPILE__
    __builtin_amdgcn_s_barrier();
#endif
}

// async global->LDS, 16B per lane; lds dest = wave-uniform base + lane*16
#define GLL16(gp, lp)                                              \
    __builtin_amdgcn_global_load_lds(                              \
        (const __attribute__((address_space(1))) void*)(gp),       \
        (__attribute__((address_space(3))) void*)(lp), 16, 0, 0)

// round-to-nearest-even fp32 -> bf16 (finite inputs only)
static __device__ __forceinline__ unsigned short f2bf(float f) {
    unsigned int u = __float_as_uint(f);
    u += 0x7fffu + ((u >> 16) & 1u);
    return (unsigned short)(u >> 16);
}

// packed fp32x2 -> bf16x2 (RNE) via gfx950 v_cvt_pk_bf16_f32 when available
static __device__ __forceinline__ unsigned int cvtpk_bf16(float lo, float hi) {
#if defined(__HIP_DEVICE_COMPILE__) && __has_builtin(__builtin_amdgcn_cvt_pk_bf16_f32)
    typedef __bf16 bf16x2 __attribute__((ext_vector_type(2)));
    bf16x2 r = __builtin_amdgcn_cvt_pk_bf16_f32(lo, hi);
    return __builtin_bit_cast(unsigned int, r);
#else
    return (unsigned int)f2bf(lo) | ((unsigned int)f2bf(hi) << 16);
#endif
}

#define LOG2E 1.44269504088896340736f

// ---------------------------------------------------------------------------
// Fused prep (R10 version): transpose+cast w_qkv/w_out (64x64 tiles, float4
// loads, padded LDS, uint4 bf16 stores), rmsnorm x->xn.
// ---------------------------------------------------------------------------
__global__ __launch_bounds__(256) void prep_k(
    const float* __restrict__ x, const float* __restrict__ gamma,
    const float* __restrict__ w_qkv, const float* __restrict__ w_out,
    unsigned short* __restrict__ xn, unsigned short* __restrict__ wtq,
    unsigned short* __restrict__ wto) {
    __shared__ float sm[64][65];  // 16640 B
    int bid = blockIdx.x, tid = threadIdx.x;
    if (bid < 1024) {  // transpose paths (block-uniform branch)
        const float* in;
        unsigned short* out;
        int R = 1024, C, bx, by;
        if (bid < 768) { in = w_qkv; out = wtq; C = 3072; bx = bid % 48; by = bid / 48; }
        else { int b2 = bid - 768; in = w_out; out = wto; C = 1024; bx = b2 % 16; by = b2 / 16; }
        int c0 = bx * 64, r0 = by * 64;
        int lr = tid >> 4, lc4 = (tid & 15) * 4;
#pragma unroll
        for (int i = 0; i < 4; i++) {
            int row = lr + i * 16;
            float4 v = *(const float4*)(in + (size_t)(r0 + row) * C + c0 + lc4);
            sm[row][lc4] = v.x;
            sm[row][lc4 + 1] = v.y;
            sm[row][lc4 + 2] = v.z;
            sm[row][lc4 + 3] = v.w;
        }
        __syncthreads();
#pragma unroll
        for (int kk = 0; kk < 2; kk++) {
            int j = (tid >> 3) + kk * 32;  // out row (= in col) 0..63
            int r8 = (tid & 7) * 8;        // out col (= in row) base
            uint4 pk;
            pk.x = cvtpk_bf16(sm[r8 + 0][j], sm[r8 + 1][j]);
            pk.y = cvtpk_bf16(sm[r8 + 2][j], sm[r8 + 3][j]);
            pk.z = cvtpk_bf16(sm[r8 + 4][j], sm[r8 + 5][j]);
            pk.w = cvtpk_bf16(sm[r8 + 6][j], sm[r8 + 7][j]);
            *(uint4*)(out + (size_t)(c0 + j) * R + r0 + r8) = pk;
        }
    } else {  // rmsnorm
        int row = bid - 1024;
        const float* xr = x + (size_t)row * 1024;
        float4 v = *(const float4*)(xr + tid * 4);
        float ss = v.x * v.x + v.y * v.y + v.z * v.z + v.w * v.w;
#pragma unroll
        for (int off = 1; off < 64; off <<= 1) ss += __shfl_xor(ss, off, 64);
        if ((tid & 63) == 0) sm[0][tid >> 6] = ss;
        __syncthreads();
        float tot = sm[0][0] + sm[0][1] + sm[0][2] + sm[0][3];
        float f = 32.0f / fmaxf(sqrtf(tot), 1e-12f);  // sqrt(1024)=32
        float4 g = *(const float4*)(gamma + tid * 4);
        uint2 o;
        o.x = cvtpk_bf16(v.x * f * g.x, v.y * f * g.y);
        o.y = cvtpk_bf16(v.z * f * g.z, v.w * f * g.w);
        *(uint2*)(xn + (size_t)row * 1024 + tid * 4) = o;
    }
}

// ---------------------------------------------------------------------------
// GEMM, round-12 structure: m97 tiles + T3/T4 counted-vmcnt prefetch.
// Old loop: stage -> __syncthreads (drains vmcnt(0)) -> compute: every
// K-step pays full staging latency serially x32 (R9 showed this drain is
// the critical path; conflicts/tile-size changes were all null).
// New loop (double-buffered LDS, raw barriers, counted vmcnt):
//   prologue: STAGE(tile0 -> buf0)
//   t: STAGE(tile t+1 -> buf[1-cb])            // issued FIRST
//      s_waitcnt vmcnt(4|3)                    // tile t done; t+1 IN FLIGHT
//      s_barrier                               // all waves' tile-t in LDS
//      ds_read buf[cb] + MFMA                  // t+1 loads fly under this
//      s_barrier                               // protect buf[cb] from t+2
// Tail waits vmcnt(0). NLOADS/wave: BM=128 -> 4, BM=64 -> 3.
// sched_barrier(0) after waitcnt (rule #18). LDS 2x16KB=32KB: 3 blocks/CU
// (grid-limited) unchanged. R7/R11: split-K closed. R5: BM=128 gemm2 closed.
// ---------------------------------------------------------------------------
template <int MODE, int BM>
__global__ __launch_bounds__(256) void gemm_bt_k(
    const unsigned short* __restrict__ A, const unsigned short* __restrict__ BT,
    float* __restrict__ C, unsigned short* __restrict__ qw,
    unsigned short* __restrict__ kw, unsigned short* __restrict__ vw,
    int M, int N, int K) {
    constexpr int RT = 4;
    constexpr int CT = (BM == 128) ? 4 : 2;
    __shared__ unsigned short As[2][BM][32];
    __shared__ unsigned short Bs[2][128][32];
    int tid = threadIdx.x;
    int wave = tid >> 6, lane = tid & 63, quad = lane >> 4, l16 = lane & 15;
    int wrb, wcb;
    if constexpr (BM == 128) { wrb = (wave >> 1) * 64; wcb = (wave & 1) * 64; }
    else { wrb = 0; wcb = wave * 32; }
    int m0 = blockIdx.y * BM, n0 = blockIdx.x * 128;
    int lrow = lane >> 2, lcol = (lane & 3) * 8;  // lane -> (row,col) in 16x32 chunk
    const unsigned short *Ag0, *Ag1 = nullptr;
    if constexpr (BM == 128) {
        Ag0 = A + (size_t)(m0 + wave * 32 + lrow) * K + lcol;
        Ag1 = A + (size_t)(m0 + wave * 32 + 16 + lrow) * K + lcol;
    } else {
        Ag0 = A + (size_t)(m0 + wave * 16 + lrow) * K + lcol;
    }
    const unsigned short* Bg0 = BT + (size_t)(n0 + wave * 32 + lrow) * K + lcol;
    const unsigned short* Bg1 = BT + (size_t)(n0 + wave * 32 + 16 + lrow) * K + lcol;

    // stage tile k0 into buffer bb (4 loads for BM=128, 3 for BM=64 per wave)
    auto stage = [&](int bb, int k0) {
        if constexpr (BM == 128) {
            GLL16(Ag0 + k0, &As[bb][wave * 32][0]);
            GLL16(Ag1 + k0, &As[bb][wave * 32 + 16][0]);
        } else {
            GLL16(Ag0 + k0, &As[bb][wave * 16][0]);
        }
        GLL16(Bg0 + k0, &Bs[bb][wave * 32][0]);
        GLL16(Bg1 + k0, &Bs[bb][wave * 32 + 16][0]);
    };

    f32x4 acc[RT][CT] = {};
    int nt = K >> 5;
    stage(0, 0);  // prologue
    for (int t = 0; t < nt; t++) {
        int cb = t & 1;
        bool pf = (t + 1 < nt);
        if (pf) stage(1 - cb, (t + 1) << 5);  // issue next tile FIRST
        if (pf) {
            if constexpr (BM == 128) wait_vmcnt_4();
            else wait_vmcnt_3();
        } else {
            wait_vmcnt_0();
        }
        raw_barrier();  // all waves' tile-t staging visible in LDS
        bf16x8 af[RT], bfr[CT];
#pragma unroll
        for (int t2 = 0; t2 < RT; t2++)
            af[t2] = *(const bf16x8*)&As[cb][wrb + t2 * 16 + l16][quad * 8];
#pragma unroll
        for (int t2 = 0; t2 < CT; t2++)
            bfr[t2] = *(const bf16x8*)&Bs[cb][wcb + t2 * 16 + l16][quad * 8];
        prio_hi();
#pragma unroll
        for (int rt = 0; rt < RT; rt++)
#pragma unroll
            for (int ct = 0; ct < CT; ct++)
                acc[rt][ct] = MFMA_K32(af[rt], bfr[ct], acc[rt][ct]);
        prio_lo();
        raw_barrier();  // reads of buf[cb] done before t+2 overwrites it
    }
#pragma unroll
    for (int rt = 0; rt < RT; rt++) {
        int mb = m0 + wrb + rt * 16 + quad * 4;
        int b = mb >> 11, nn = mb & 2047;
#pragma unroll
        for (int ct = 0; ct < CT; ct++) {
            int col = n0 + wcb + ct * 16 + l16;
            if (MODE == 0) {
#pragma unroll
                for (int r = 0; r < 4; r++)
                    C[(size_t)(mb + r) * N + col] = acc[rt][ct][r];
            } else {
                int sec = col >> 10, ci = col & 1023;
                int hh = ci >> 6, dd = ci & 63;
                int bh = b * 16 + hh;
                if (sec == 0) {
#pragma unroll
                    for (int r = 0; r < 4; r++)
                        qw[((size_t)bh * 2048 + nn + r) * 64 + dd] =
                            f2bf(acc[rt][ct][r] * (0.125f * LOG2E));
                } else if (sec == 1) {
#pragma unroll
                    for (int r = 0; r < 4; r++)
                        kw[((size_t)bh * 2048 + nn + r) * 64 + dd] = f2bf(acc[rt][ct][r]);
                } else {
                    uint2 pk;
                    pk.x = cvtpk_bf16(acc[rt][ct][0], acc[rt][ct][1]);
                    pk.y = cvtpk_bf16(acc[rt][ct][2], acc[rt][ct][3]);
                    *(uint2*)&vw[((size_t)bh * 64 + dd) * 2048 + nn] = pk;
                }
            }
        }
    }
}

// ---------------------------------------------------------------------------
// Causal flash attention, key-split 8-wave blocks (R6 structure, EXACT —
// proven 46.4-46.7us across R6-R11). Chain-cut softmax (per-lane max;
// scalar __any ballot gates rare reduce+rescale; P bounded by 2^8, T13),
// per-lane lrun reduced once in epilogue, KVBLK=32, 1 barrier/tile, dbuf +
// reg prefetch. Groups of 4 waves split the key range; merge via LDS
// (fully-masked rows killed by a1->0). (512,4): VGPR 40 -> 4 blocks/CU.
// R8: KVBLK=64 cut residency, regressed; closed.
// ---------------------------------------------------------------------------
__global__ __launch_bounds__(512, 4) void attn_k(
    const unsigned short* __restrict__ q, const unsigned short* __restrict__ k,
    const unsigned short* __restrict__ vt, unsigned short* __restrict__ o) {
    // LDS union: [group][buf] K tiles (32x64, pad 72) + V tiles (64x32, pad 40);
    // epilogue overlays Osm[64][68] f32 on the K region, msm/lsm on V region.
    __shared__ __align__(16) char smem[38912];
    typedef unsigned short ush;
    ush(*Ks)[2][32][72] = (ush(*)[2][32][72])smem;            // 18432 B
    ush(*Vt)[2][64][40] = (ush(*)[2][64][40])(smem + 18432);  // 20480 B
    float(*Osm)[68] = (float(*)[68])smem;                     // 17408 B (<= K region)
    float* msm = (float*)(smem + 18432);                      // 256 B (in V region)
    float* lsm = msm + 64;

    int bh = blockIdx.x;
    int qt = 31 - (int)blockIdx.y;  // heavy-first LPT order
    int tid = threadIdx.x, wave = tid >> 6, lane = tid & 63;
    int quad = lane >> 4, l16 = lane & 15;
    int g = wave >> 2, wq = wave & 3;
    int b = bh >> 4, h = bh & 15;
    const ush* qg = q + (size_t)bh * 2048 * 64;
    const ush* kg = k + (size_t)bh * 2048 * 64;
    const ush* vg = vt + (size_t)bh * 64 * 2048;

    // staging map: 256 threads/group; K: 32 rows x 64 cols; V: 64 d x 32 keys
    int ti = wq * 64 + lane;
    int kr = ti >> 3, kc = (ti & 7) * 8;
    int vr = ti >> 2, vc = (ti & 3) * 8;
    const ush* Kg = kg + (size_t)kr * 64 + kc;
    const ush* Vg = vg + (size_t)vr * 2048 + vc;

    int row_l = wq * 16 + l16;    // local q row 0..63
    int q0w = qt * 64 + wq * 16;  // global q row base for this wave
    bf16x8 bq[2];                 // Q^T B-operand: [k=d=ks*32+quad*8+j][n=qrow=l16]
#pragma unroll
    for (int ks = 0; ks < 2; ks++)
        bq[ks] = *(const bf16x8*)&qg[(size_t)(q0w + l16) * 64 + ks * 32 + quad * 8];

    f32x4 ot[4] = {};                 // Ot C-layout: [d=dt*16+quad*4+r][qrow=l16]
    float mrun = -1e30f, lrun = 0.f;  // lrun is a PER-LANE partial (reduced at end)
    int nT = qt + 1;                  // tiles per group (equal for both groups)
    int kt0 = g ? (qt + 1) : 0;

    u16x8 pk, pv;  // prefetch registers
    // preload first tile into buf 0
    pk = *(const u16x8*)(Kg + (size_t)kt0 * 2048);
    pv = *(const u16x8*)(Vg + kt0 * 32);
    *(u16x8*)&Ks[g][0][kr][kc] = pk;
    *(u16x8*)&Vt[g][0][vr][vc] = pv;
    __syncthreads();

    for (int i = 0; i < nT; i++) {
        int cb = i & 1, kt = kt0 + i;
        bool pf = (i + 1 < nT);
        if (pf) {  // issue next tile's global loads early (wave-uniform branch)
            pk = *(const u16x8*)(Kg + (size_t)(kt + 1) * 2048);
            pv = *(const u16x8*)(Vg + (kt + 1) * 32);
        }
        // St[key=ct*16+quad*4+r][qrow=l16] = K . Q^T
        f32x4 sf[2];
        prio_hi();
#pragma unroll
        for (int ct = 0; ct < 2; ct++) {
            bf16x8 ak0 = *(const bf16x8*)&Ks[g][cb][ct * 16 + l16][quad * 8];
            bf16x8 ak1 = *(const bf16x8*)&Ks[g][cb][ct * 16 + l16][32 + quad * 8];
            f32x4 s = {};
            s = MFMA_K32(ak0, bq[0], s);
            s = MFMA_K32(ak1, bq[1], s);
            sf[ct] = s;
        }
        prio_lo();
        if (kt >= 2 * qt) {  // tiles that can touch the diagonal
#pragma unroll
            for (int ct = 0; ct < 2; ct++)
#pragma unroll
                for (int r = 0; r < 4; r++)
                    if (kt * 32 + ct * 16 + quad * 4 + r > qt * 64 + row_l)
                        sf[ct][r] = -1e30f;
        }
        // chain-cut online softmax (exp2 domain; log2e pre-folded into q):
        // per-lane max only in the common path; no DS shuffles.
        float t0 = fmaxf(sf[0][0], sf[0][1]), t1 = fmaxf(sf[0][2], sf[0][3]);
        float t2 = fmaxf(sf[1][0], sf[1][1]), t3 = fmaxf(sf[1][2], sf[1][3]);
        float mx_l = fmaxf(fmaxf(t0, t1), fmaxf(t2, t3));
        if (__any(mx_l > mrun + 8.0f)) {  // rare: full reduce + rescale
            float mx = fmaxf(mx_l, __shfl_xor(mx_l, 16, 64));
            mx = fmaxf(mx, __shfl_xor(mx, 32, 64));
            float mnew = fmaxf(mrun, mx);
            float al = fast_exp2(mrun - mnew);
            mrun = mnew;
            lrun *= al;
#pragma unroll
            for (int dt = 0; dt < 4; dt++)
#pragma unroll
                for (int r = 0; r < 4; r++) ot[dt][r] *= al;
        }
        float rs = 0.f;
#pragma unroll
        for (int ct = 0; ct < 2; ct++)
#pragma unroll
            for (int r = 0; r < 4; r++) {
                float p = fast_exp2(sf[ct][r] - mrun);  // bounded by 2^8
                sf[ct][r] = p;
                rs += p;
            }
        lrun += rs;  // per-lane partial; cross-quad reduce deferred to epilogue
        // P -> packed bf16 B-fragments for 16x16x16 (k=quad*4+j = C-layout)
        s16x4 bpr[2];
#pragma unroll
        for (int ct = 0; ct < 2; ct++) {
            uint2 u;
            u.x = cvtpk_bf16(sf[ct][0], sf[ct][1]);
            u.y = cvtpk_bf16(sf[ct][2], sf[ct][3]);
            bpr[ct] = __builtin_bit_cast(s16x4, u);
        }
        // Ot += V^T * P^T
        prio_hi();
#pragma unroll
        for (int dt = 0; dt < 4; dt++) {
#pragma unroll
            for (int ct = 0; ct < 2; ct++) {
                s16x4 av = *(const s16x4*)&Vt[g][cb][dt * 16 + l16][ct * 16 + quad * 4];
                ot[dt] = mfma_k16(av, bpr[ct], ot[dt]);
            }
        }
        prio_lo();
        if (pf) {  // write prefetched tile to the other buffer
            *(u16x8*)&Ks[g][1 - cb][kr][kc] = pk;
            *(u16x8*)&Vt[g][1 - cb][vr][vc] = pv;
        }
        __syncthreads();  // single barrier per tile
    }

    // deferred cross-quad sum reduce (once, instead of 2 shuffles per tile)
    lrun += __shfl_xor(lrun, 16, 64);
    lrun += __shfl_xor(lrun, 32, 64);

    // ---- cross-group merge (group 1 -> LDS, group 0 combines + writes) ----
    if (g == 1) {
        msm[row_l] = mrun;  // quads duplicate-write identical values: benign
        lsm[row_l] = lrun;
#pragma unroll
        for (int dt = 0; dt < 4; dt++)
            *(f32x4*)&Osm[row_l][dt * 16 + quad * 4] = ot[dt];
    }
    __syncthreads();
    if (g == 0) {
        float m1 = msm[row_l], l1 = lsm[row_l];
        float mmax = fmaxf(mrun, m1);
        float a0 = fast_exp2(mrun - mmax), a1 = fast_exp2(m1 - mmax);
        float inv = 1.0f / (a0 * lrun + a1 * l1);
        float s0 = a0 * inv, s1 = a1 * inv;
        size_t rowbase = ((size_t)b * 2048 + qt * 64 + row_l) * 1024 + h * 64;
#pragma unroll
        for (int dt = 0; dt < 4; dt++) {
            f32x4 o1 = *(const f32x4*)&Osm[row_l][dt * 16 + quad * 4];
            uint2 pkk;
            pkk.x = cvtpk_bf16(ot[dt][0] * s0 + o1[0] * s1,
                               ot[dt][1] * s0 + o1[1] * s1);
            pkk.y = cvtpk_bf16(ot[dt][2] * s0 + o1[2] * s1,
                               ot[dt][3] * s0 + o1[3] * s1);
            *(uint2*)&o[rowbase + dt * 16 + quad * 4] = pkk;
        }
    }
}

extern "C" void kernel_launch(void* const* d_in, const int* in_sizes, int n_in,
                              void* d_out, int out_size, void* d_ws, size_t ws_size,
                              hipStream_t stream) {
    const float* x = (const float*)d_in[0];       // [2,2048,1024]
    const float* gamma = (const float*)d_in[1];   // [1024]
    const float* w_qkv = (const float*)d_in[2];   // [1024,3072]
    const float* w_out = (const float*)d_in[3];   // [1024,1024]
    float* out = (float*)d_out;                   // [2,2048,1024] fp32
    char* ws = (char*)d_ws;

    unsigned short* xn = (unsigned short*)(ws);              // 8 MB (reused as ao)
    unsigned short* wtq = (unsigned short*)(ws + 8388608);   // 6 MB  [3072][1024]
    unsigned short* wto = (unsigned short*)(ws + 14680064);  // 2 MB  [1024][1024]
    unsigned short* qw = (unsigned short*)(ws + 16777216);   // 8 MB  [32][2048][64]
    unsigned short* kw = (unsigned short*)(ws + 25165824);   // 8 MB  [32][2048][64]
    unsigned short* vw = (unsigned short*)(ws + 33554432);   // 8 MB  [32][64][2048]
    unsigned short* ao = xn;                                 // reuse after QKV GEMM

    prep_k<<<5120, 256, 0, stream>>>(x, gamma, w_qkv, w_out, xn, wtq, wto);
    gemm_bt_k<1, 128><<<dim3(24, 32), 256, 0, stream>>>(xn, wtq, nullptr, qw, kw, vw,
                                                        4096, 3072, 1024);
    attn_k<<<dim3(32, 32), 512, 0, stream>>>(qw, kw, vw, ao);
    gemm_bt_k<0, 64><<<dim3(8, 64), 256, 0, stream>>>(ao, wto, out, nullptr, nullptr,
                                                      nullptr, 4096, 1024, 1024);
}